// Round 2
// baseline (111.839 us; speedup 1.0000x reference)
//
#include <hip/hip_runtime.h>
#include <hip/hip_bf16.h>

#define B_ROWS 4096
#define C_CLS  1000
#define D_DIM  2048
#define NPAD   1024
#define KSPLIT 4
#define KCHUNK (D_DIM / KSPLIT)   // 512

typedef __attribute__((ext_vector_type(8))) short s16x8;
typedef __attribute__((ext_vector_type(4))) float f32x4;

__device__ __forceinline__ unsigned short f2bf(float f) {
    __hip_bfloat16 h = __float2bfloat16(f);
    unsigned short u;
    __builtin_memcpy(&u, &h, 2);
    return u;
}

// Kernel 1: W (1000x2048 fp32) -> Wb (1024x2048 bf16, padded rows zero) + sq_w fp32
__global__ __launch_bounds__(256) void prep_kernel(const float* __restrict__ W,
                                                   unsigned short* __restrict__ Wb,
                                                   float* __restrict__ sqw) {
    const int row = blockIdx.x;
    const int tid = threadIdx.x;
    unsigned short* wrow = Wb + (size_t)row * D_DIM;
    if (row >= C_CLS) {
        uint4 z; z.x = z.y = z.z = z.w = 0u;
        *reinterpret_cast<uint4*>(wrow + tid * 8) = z;
        if (tid == 0) sqw[row] = 0.f;
        return;
    }
    const float* wr = W + (size_t)row * D_DIM;
    float4 x0 = *reinterpret_cast<const float4*>(wr + tid * 8);
    float4 x1 = *reinterpret_cast<const float4*>(wr + tid * 8 + 4);
    float s = x0.x * x0.x + x0.y * x0.y + x0.z * x0.z + x0.w * x0.w
            + x1.x * x1.x + x1.y * x1.y + x1.z * x1.z + x1.w * x1.w;
    union { unsigned short u[8]; uint4 v; } pk;
    pk.u[0] = f2bf(x0.x); pk.u[1] = f2bf(x0.y); pk.u[2] = f2bf(x0.z); pk.u[3] = f2bf(x0.w);
    pk.u[4] = f2bf(x1.x); pk.u[5] = f2bf(x1.y); pk.u[6] = f2bf(x1.z); pk.u[7] = f2bf(x1.w);
    *reinterpret_cast<uint4*>(wrow + tid * 8) = pk.v;
#pragma unroll
    for (int off = 32; off > 0; off >>= 1) s += __shfl_down(s, off);
    __shared__ float sv[4];
    const int lane = tid & 63, wid = tid >> 6;
    if (lane == 0) sv[wid] = s;
    __syncthreads();
    if (tid == 0) sqw[row] = sv[0] + sv[1] + sv[2] + sv[3];
}

// Kernel 2: split-K Gram partials. part[kz][a][c] = sum_{k in chunk kz} Wb[a][k]*Wb[c][k]
// Grid (16,16,KSPLIT), block 256 (4 waves), block tile 64x64, wave tile 32x32.
__global__ __launch_bounds__(256) void dist_partial_kernel(const unsigned short* __restrict__ Wb,
                                                           float* __restrict__ part) {
    const int tid  = threadIdx.x;
    const int lane = tid & 63;
    const int wid  = tid >> 6;       // 0..3
    const int wm   = wid >> 1;       // 0..1
    const int wn   = wid & 1;        // 0..1
    const int l16  = lane & 15;
    const int quad = lane >> 4;      // 0..3
    const int base_m = blockIdx.y * 64 + wm * 32;
    const int base_n = blockIdx.x * 64 + wn * 32;
    const int k0 = blockIdx.z * KCHUNK;

    f32x4 acc00 = {0.f, 0.f, 0.f, 0.f};
    f32x4 acc01 = {0.f, 0.f, 0.f, 0.f};
    f32x4 acc10 = {0.f, 0.f, 0.f, 0.f};
    f32x4 acc11 = {0.f, 0.f, 0.f, 0.f};

    const unsigned short* arow0 = Wb + (size_t)(base_m + l16) * D_DIM + k0 + quad * 8;
    const unsigned short* arow1 = arow0 + (size_t)16 * D_DIM;
    const unsigned short* brow0 = Wb + (size_t)(base_n + l16) * D_DIM + k0 + quad * 8;
    const unsigned short* brow1 = brow0 + (size_t)16 * D_DIM;

    for (int k = 0; k < KCHUNK; k += 32) {
        s16x8 a0 = *reinterpret_cast<const s16x8*>(arow0 + k);
        s16x8 a1 = *reinterpret_cast<const s16x8*>(arow1 + k);
        s16x8 b0 = *reinterpret_cast<const s16x8*>(brow0 + k);
        s16x8 b1 = *reinterpret_cast<const s16x8*>(brow1 + k);
        acc00 = __builtin_amdgcn_mfma_f32_16x16x32_bf16(a0, b0, acc00, 0, 0, 0);
        acc01 = __builtin_amdgcn_mfma_f32_16x16x32_bf16(a0, b1, acc01, 0, 0, 0);
        acc10 = __builtin_amdgcn_mfma_f32_16x16x32_bf16(a1, b0, acc10, 0, 0, 0);
        acc11 = __builtin_amdgcn_mfma_f32_16x16x32_bf16(a1, b1, acc11, 0, 0, 0);
    }

    float* pbase = part + (size_t)blockIdx.z * NPAD * NPAD;
    f32x4 accs[2][2] = {{acc00, acc01}, {acc10, acc11}};
#pragma unroll
    for (int mt = 0; mt < 2; ++mt) {
#pragma unroll
        for (int nt = 0; nt < 2; ++nt) {
#pragma unroll
            for (int r = 0; r < 4; ++r) {
                const int ga = base_m + mt * 16 + quad * 4 + r;   // C/D: row = quad*4+reg
                const int gc = base_n + nt * 16 + l16;            // C/D: col = lane&15
                pbase[(size_t)ga * NPAD + gc] = accs[mt][nt][r];
            }
        }
    }
}

// Kernel 3: dist[a][c] = k*sqrt(max(sq[a]+sq[c]-2*sum_kz part,0)). Grid 1024, block 256.
__global__ __launch_bounds__(256) void combine_kernel(const float* __restrict__ part,
                                                      const float* __restrict__ sqw,
                                                      const float* __restrict__ Kin,
                                                      float* __restrict__ dist) {
    const int a = blockIdx.x;
    const int c = threadIdx.x * 4;
    const size_t off = (size_t)a * NPAD + c;
    const size_t N2 = (size_t)NPAD * NPAD;
    f32x4 p0 = *reinterpret_cast<const f32x4*>(part + off);
    f32x4 p1 = *reinterpret_cast<const f32x4*>(part + N2 + off);
    f32x4 p2 = *reinterpret_cast<const f32x4*>(part + 2 * N2 + off);
    f32x4 p3 = *reinterpret_cast<const f32x4*>(part + 3 * N2 + off);
    f32x4 sc = *reinterpret_cast<const f32x4*>(sqw + c);
    const float sqa = sqw[a];
    const float kscale = Kin[0] * 4.4642857142857144f;  // DATA_SCALING = 1/0.224
    f32x4 d;
#pragma unroll
    for (int t = 0; t < 4; ++t) {
        float d2 = sqa + sc[t] - 2.0f * (p0[t] + p1[t] + p2[t] + p3[t]);
        d[t] = kscale * __builtin_sqrtf(fmaxf(d2, 0.f));
    }
    *reinterpret_cast<f32x4*>(dist + off) = d;
}

// Kernel 4: one wave per prediction row, all-register, no barriers.
__global__ __launch_bounds__(256) void final_kernel(const float* __restrict__ pred,
                                                    const float* __restrict__ dist,
                                                    float* __restrict__ out) {
    const int lane = threadIdx.x & 63;
    const int wid  = threadIdx.x >> 6;
    const int row  = blockIdx.x * 4 + wid;
    const float* p = pred + (size_t)row * C_CLS;   // 4000 B row stride, 16 B aligned

    f32x4 v[4];
    float best = -INFINITY;
    int   bi   = 0x7fffffff;
#pragma unroll
    for (int j = 0; j < 4; ++j) {
        const int idx4 = lane + 64 * j;           // float4 index, 250 total
        if (idx4 < 250) {
            v[j] = *reinterpret_cast<const f32x4*>(p + idx4 * 4);
#pragma unroll
            for (int t = 0; t < 4; ++t) {
                const int c = idx4 * 4 + t;
                if (v[j][t] > best) { best = v[j][t]; bi = c; }
            }
        } else {
            v[j] = f32x4{-INFINITY, -INFINITY, -INFINITY, -INFINITY};
        }
    }
#pragma unroll
    for (int off = 32; off > 0; off >>= 1) {
        float ov = __shfl_down(best, off);
        int   oi = __shfl_down(bi, off);
        if (ov > best || (ov == best && oi < bi)) { best = ov; bi = oi; }
    }
    const float y0 = __shfl(best, 0);
    const int   j0 = __shfl(bi, 0);

    const float* drow = dist + (size_t)j0 * NPAD;
    float rmin = INFINITY;
#pragma unroll
    for (int j = 0; j < 4; ++j) {
        const int idx4 = lane + 64 * j;
        if (idx4 < 250) {
            f32x4 d = *reinterpret_cast<const f32x4*>(drow + idx4 * 4);
#pragma unroll
            for (int t = 0; t < 4; ++t) {
                const int c = idx4 * 4 + t;
                if (c != j0) rmin = fminf(rmin, (y0 - v[j][t]) / d[t]);
            }
        }
    }
#pragma unroll
    for (int off = 32; off > 0; off >>= 1) rmin = fminf(rmin, __shfl_down(rmin, off));
    if (lane == 0) out[row] = rmin;
}

extern "C" void kernel_launch(void* const* d_in, const int* in_sizes, int n_in,
                              void* d_out, int out_size, void* d_ws, size_t ws_size,
                              hipStream_t stream) {
    const float* pred = (const float*)d_in[0];   // (4096, 1000) fp32
    const float* W    = (const float*)d_in[1];   // (1000, 2048) fp32
    const float* K    = (const float*)d_in[2];   // (1,) fp32
    float* out = (float*)d_out;                  // (4096,) fp32

    char* ws = (char*)d_ws;
    unsigned short* Wb = (unsigned short*)ws;                     // 4 MB
    size_t o = (size_t)NPAD * D_DIM * 2;
    float* dist = (float*)(ws + o);  o += (size_t)NPAD * NPAD * 4;        // 4 MB
    float* part = (float*)(ws + o);  o += (size_t)KSPLIT * NPAD * NPAD * 4; // 16 MB
    float* sqw  = (float*)(ws + o);                                        // 4 KB

    prep_kernel<<<NPAD, 256, 0, stream>>>(W, Wb, sqw);
    dist_partial_kernel<<<dim3(NPAD / 64, NPAD / 64, KSPLIT), 256, 0, stream>>>(Wb, part);
    combine_kernel<<<NPAD, 256, 0, stream>>>(part, sqw, K, dist);
    final_kernel<<<B_ROWS / 4, 256, 0, stream>>>(pred, dist, out);
}